// Round 11
// baseline (219.682 us; speedup 1.0000x reference)
//
#include <hip/hip_runtime.h>

// GCN 2-layer + mean-pool + readout.
// Algebra: aggregation is linear, so transform FIRST:
//   Y      = (norm_out ⊙ X) @ W1            (dense register-tiled GEMM, fp32)
//   h1[n]  = relu( norm_in[n] * sum_{e:dst=n} Y[src_e] + b1 )
//   out    = ((1/N) * sum_u c[u]*h1[u]) @ W2 + b2  @ Wr^T + br
//   c[u]   = norm_out[u] * sum_{e:src=u} norm_in[dst_e]
//
// No per-edge device-scope atomics (each moves a 64B line at the coherence
// point). Two-level binning preproc (k_part reorder-then-flush, k_csr LDS-
// staged, k_bin_src) unchanged from round 10.
//
// Round-10 lesson: k_agg pinned at 59us across ILP/FETCH variants -> cost =
// panels x line-requests. NEW GEOMETRY: 6 panels of 16 cols (3.2MB, L2-fit):
// each edge-row is ONE aligned 64B line (was 3x16B spanning 1.5 lines), all
// 32 lanes active, and only 6 sweeps instead of 8. Panel->XCD: XCD p<6 owns
// panel p; XCDs 6,7 duplicate panels 0,1 on a disjoint node half (L2s cache
// independently). Summation trees identical -> bitwise-same results.
//
// Pipeline: memset(26KB) -> k_part -> k_csr -> k_bin_src -> k_xform ->
//           k_agg -> k_final.   (7 dispatches)

constexpr int NN = 50000;
constexpr int NE = 800000;
constexpr int NB = 196;         // buckets of 256 nodes
constexpr int CAP = 6144;       // bucket capacity (mean 4082, +32 sigma)

// ws layout in 4-byte units:
constexpr int OFF_SVEC     = 0;        // float[256]  (zeroed)
constexpr int OFF_BCURD    = 256;      // int[196*16] line-padded (zeroed)
constexpr int OFF_BCURS    = 3392;     // int[196*16] line-padded (zeroed)
constexpr int OFF_NORM_OUT = 6528;     // float[50000]
constexpr int OFF_NORM_IN  = 56528;    // float[50000]
constexpr int OFF_CW       = 106528;   // float[50000]
constexpr int OFF_ROW_PTR  = 156528;   // int[50001] -> pad 206532
constexpr int OFF_EDGE_SRC = 206532;   // ushort[800000] = 400000 ints -> 606532
constexpr int OFF_PD       = 606532;   // int[196*6144] (dead after k_csr)
constexpr int OFF_PS       = 1810756;  // int[196*6144] (dead after k_bin_src)
constexpr int OFF_YP       = 606532;   // float[6][50000][16] aliases PD+PS
                                       // end 5406532 words = 21.6MB (proven ws)
constexpr size_t ZERO_BYTES = (size_t)(OFF_NORM_OUT) * 4;   // svec + cursors

// Dual partition with LDS reorder-then-flush (coalesced bucket-run writes).
__global__ __launch_bounds__(256)
void k_part(const int* __restrict__ src, const int* __restrict__ dst,
            int* __restrict__ bcur_d, int* __restrict__ bcur_s,
            int* __restrict__ pd, int* __restrict__ ps) {
  __shared__ int hd[256], hs[256], gd[256], gs[256];
  __shared__ int ldx[256], cur[256], scn[256];
  __shared__ int stage[2048];
  __shared__ unsigned char stageB[2048];
  const int t = threadIdx.x;
  hd[t] = 0; hs[t] = 0;
  __syncthreads();
  const int e0 = blockIdx.x * 2048;
  int s_[8], d_[8];
#pragma unroll
  for (int i = 0; i < 8; ++i) {
    int e = e0 + i * 256 + t;
    bool v = e < NE;
    s_[i] = v ? src[e] : -1;
    d_[i] = v ? dst[e] : -1;
    if (v) { atomicAdd(&hd[d_[i] >> 8], 1); atomicAdd(&hs[s_[i] >> 8], 1); }
  }
  __syncthreads();
  if (t < NB) {
    int c = hd[t];
    gd[t] = c ? (t * CAP + atomicAdd(&bcur_d[t * 16], c)) : 0;
    c = hs[t];
    gs[t] = c ? (t * CAP + atomicAdd(&bcur_s[t * 16], c)) : 0;
  }

  // ---- dst partition: scan -> LDS place -> linear flush ----
  scn[t] = hd[t];
  __syncthreads();
  for (int off = 1; off < 256; off <<= 1) {
    int u = (t >= off) ? scn[t - off] : 0;
    __syncthreads();
    scn[t] += u;
    __syncthreads();
  }
  ldx[t] = scn[t] - hd[t];
  cur[t] = scn[t] - hd[t];
  const int totd = scn[255];
  __syncthreads();
#pragma unroll
  for (int i = 0; i < 8; ++i) {
    if (d_[i] >= 0) {
      int B = d_[i] >> 8;
      int p = atomicAdd(&cur[B], 1);             // LDS
      stage[p] = (s_[i] << 8) | (d_[i] & 255);
      stageB[p] = (unsigned char)B;
    }
  }
  __syncthreads();
  for (int j = t; j < totd; j += 256) {          // coalesced within runs
    int B = stageB[j];
    pd[gd[B] + (j - ldx[B])] = stage[j];
  }
  __syncthreads();

  // ---- src partition: same machinery, reusing stage ----
  scn[t] = hs[t];
  __syncthreads();
  for (int off = 1; off < 256; off <<= 1) {
    int u = (t >= off) ? scn[t - off] : 0;
    __syncthreads();
    scn[t] += u;
    __syncthreads();
  }
  ldx[t] = scn[t] - hs[t];
  cur[t] = scn[t] - hs[t];
  const int tots = scn[255];
  __syncthreads();
#pragma unroll
  for (int i = 0; i < 8; ++i) {
    if (s_[i] >= 0) {
      int B = s_[i] >> 8;
      int p = atomicAdd(&cur[B], 1);             // LDS
      stage[p] = (d_[i] << 8) | (s_[i] & 255);
      stageB[p] = (unsigned char)B;
    }
  }
  __syncthreads();
  for (int j = t; j < tots; j += 256) {
    int B = stageB[j];
    ps[gs[B] + (j - ldx[B])] = stage[j];
  }
}

// Fused CSR builder per bucket: stage entries in LDS ONCE -> hist -> base
// reduce -> 256-wide scan -> row_ptr + norm_in + cursors -> placement.
__global__ __launch_bounds__(256)
void k_csr(const int* __restrict__ pd, const int* __restrict__ bcur_d,
           int* __restrict__ row_ptr, float* __restrict__ norm_in,
           unsigned short* __restrict__ edge_src) {
  __shared__ int pe_s[CAP];                      // 24KB bucket staging
  __shared__ int hist[256], cur[256], sc[256];
  const int t = threadIdx.x, b = blockIdx.x;
  hist[t] = 0;
  __syncthreads();
  const int cnt = bcur_d[b * 16];
  const int* pe = pd + b * CAP;
  for (int i = t; i < cnt; i += 256) {
    int p = pe[i];                               // single coalesced global read
    pe_s[i] = p;
    atomicAdd(&hist[p & 255], 1);
  }

  // bucket base = sum of bucket counts below b
  sc[t] = (t < b) ? bcur_d[t * 16] : 0;          // b <= 195 < 256
  __syncthreads();
  for (int s = 128; s > 0; s >>= 1) {
    if (t < s) sc[t] += sc[t + s];
    __syncthreads();
  }
  const int base0 = sc[0];
  __syncthreads();

  // 256-wide Hillis-Steele scan of hist
  int h = hist[t];
  sc[t] = h;
  __syncthreads();
  for (int off = 1; off < 256; off <<= 1) {
    int u = (t >= off) ? sc[t - off] : 0;
    __syncthreads();
    sc[t] += u;
    __syncthreads();
  }
  int excl = base0 + sc[t] - h;
  int n = b * 256 + t;
  if (n < NN) {
    row_ptr[n] = excl;
    norm_in[n] = 1.0f / sqrtf((float)max(h, 1));
  }
  cur[t] = excl;
  __syncthreads();
  if (b == NB - 1 && t == 0) row_ptr[NN] = base0 + cnt;

  // placement from LDS (ushort: node ids < 65536)
  for (int i = t; i < cnt; i += 256) {
    int p = pe_s[i];
    int pos = atomicAdd(&cur[p & 255], 1);       // LDS
    edge_src[pos] = (unsigned short)(p >> 8);
  }
}

// Per-bucket out-degree + c_raw (LDS atomics; norm_in gathers are L2-hot),
// emits norm_out and cw = norm_out * c_raw.
__global__ __launch_bounds__(256)
void k_bin_src(const int* __restrict__ ps, const int* __restrict__ bcur_s,
               const float* __restrict__ norm_in,
               float* __restrict__ norm_out, float* __restrict__ cw) {
  __shared__ int dout[256];
  __shared__ float craw[256];
  const int t = threadIdx.x, b = blockIdx.x;
  dout[t] = 0; craw[t] = 0.f;
  __syncthreads();
  const int cnt = bcur_s[b * 16];
  const int* pe = ps + b * CAP;
  for (int i = t; i < cnt; i += 256) {
    int p = pe[i];
    atomicAdd(&dout[p & 255], 1);                // LDS
    atomicAdd(&craw[p & 255], norm_in[p >> 8]);  // LDS float add
  }
  __syncthreads();
  int n = b * 256 + t;
  if (n < NN) {
    float no = 1.0f / sqrtf((float)max(dout[t], 1));
    norm_out[n] = no;
    cw[n] = no * craw[t];
  }
}

// Y = (norm_out ⊙ X) @ W1 — register-tiled GEMM, 6x16-col panel output.
// Thread (tn=t&7, tm=t>>3) computes 2 nodes x 12 cols; each 4-col quad lands
// in panel col>>4 at row offset col&15 (16-float rows, all float4-aligned).
__global__ __launch_bounds__(256, 6)
void k_xform(const float* __restrict__ feats, const float* __restrict__ norm_out,
             const float* __restrict__ W1, float* __restrict__ YP) {
  __shared__ float XT[96][68];            // [k][node], pad 64->68
  const int t = threadIdx.x;
  const int nb = blockIdx.x * 64;         // tile base node

  const float4* f4 = (const float4*)feats;
#pragma unroll
  for (int i = 0; i < 6; ++i) {           // 6*256 = 1536 float4 = 64x96 floats
    int idx4 = i * 256 + t;
    int n = idx4 / 24;
    int kq = idx4 % 24;
    int ng = nb + n;
    float4 v = make_float4(0.f, 0.f, 0.f, 0.f);
    float no = 0.f;
    if (ng < NN) { v = f4[(size_t)ng * 24 + kq]; no = norm_out[ng]; }
    XT[kq * 4 + 0][n] = v.x * no;
    XT[kq * 4 + 1][n] = v.y * no;
    XT[kq * 4 + 2][n] = v.z * no;
    XT[kq * 4 + 3][n] = v.w * no;
  }
  __syncthreads();

  const int tn = t & 7;                   // column chunk: cols 12*tn..12*tn+11
  const int tm = t >> 3;                  // node pair: nodes 2*tm, 2*tm+1
  float acc0[12], acc1[12];
#pragma unroll
  for (int c = 0; c < 12; ++c) { acc0[c] = 0.f; acc1[c] = 0.f; }

  const float4* W4 = (const float4*)(W1 + 12 * tn);   // row stride 24 float4
#pragma unroll 4
  for (int k = 0; k < 96; ++k) {
    float2 x = *(const float2*)&XT[k][2 * tm];
    float4 w0 = W4[k * 24 + 0];
    float4 w1 = W4[k * 24 + 1];
    float4 w2 = W4[k * 24 + 2];
    const float w[12] = {w0.x, w0.y, w0.z, w0.w, w1.x, w1.y, w1.z, w1.w,
                         w2.x, w2.y, w2.z, w2.w};
#pragma unroll
    for (int c = 0; c < 12; ++c) {
      acc0[c] = fmaf(x.x, w[c], acc0[c]);
      acc1[c] = fmaf(x.y, w[c], acc1[c]);
    }
  }

  int n0 = nb + 2 * tm;
#pragma unroll
  for (int c4 = 0; c4 < 3; ++c4) {
    int col = 12 * tn + 4 * c4;
    int p = col >> 4, off = col & 15;
    float* base = YP + ((size_t)p * NN) * 16 + off;
    if (n0 < NN)
      *(float4*)(base + (size_t)n0 * 16) =
          make_float4(acc0[4 * c4], acc0[4 * c4 + 1], acc0[4 * c4 + 2], acc0[4 * c4 + 3]);
    if (n0 + 1 < NN)
      *(float4*)(base + (size_t)(n0 + 1) * 16) =
          make_float4(acc1[4 * c4], acc1[4 * c4 + 1], acc1[4 * c4 + 2], acc1[4 * c4 + 3]);
  }
}

// Panel-per-XCD CSR gather, 6 panels of 16 cols. Each edge-row = one aligned
// 64B line; 32 lanes = 8 edge slots x 4 quads. XCDs 6,7 duplicate panels 0,1
// over the second half of the node slots. Node-pair ILP retained.
__global__ __launch_bounds__(256, 6)
void k_agg(const float* __restrict__ YP,
           const float* __restrict__ norm_in, const float* __restrict__ cw,
           const int* __restrict__ row_ptr, const unsigned short* __restrict__ edge_src,
           const float* __restrict__ b1, float* __restrict__ svec) {
  __shared__ float red[16];
  const int tid = threadIdx.x;
  if (tid < 16) red[tid] = 0.f;
  __syncthreads();

  const int xcd   = blockIdx.x & 7;
  const int bp    = blockIdx.x >> 3;        // 0..255
  const int panel = (xcd < 6) ? xcd : (xcd - 6);      // 6,7 -> 0,1
  const int slotb = (xcd >= 6) ? 256 : 0;
  const int nslot = (panel < 2) ? 512 : 256;
  const int stride = nslot * 8;             // 4096 or 2048

  const int g = tid >> 5, l = tid & 31;
  const int ei = l >> 2;                    // edge slot 0..7
  const int q4 = (l & 3) * 4;               // quad offset within 16-float row

  const float* Yp = YP + (size_t)panel * NN * 16;
  float4 b4 = make_float4(0.f, 0.f, 0.f, 0.f);
  if (l < 4) b4 = ((const float4*)b1)[4 * panel + l];  // cols 16p+4l..+3

  float a0 = 0.f, a1 = 0.f, a2 = 0.f, a3 = 0.f;

  const int gid = (slotb + bp) * 8 + g;
  for (int n = gid; n < NN; n += 2 * stride) {
    const int m = n + stride;
    const bool hb = (m < NN);
    int e1a = row_ptr[n + 1], basea = row_ptr[n];
    int e1b = 0, baseb = 0;
    if (hb) { e1b = row_ptr[m + 1]; baseb = row_ptr[m]; }
    float va0 = 0.f, va1 = 0.f, va2 = 0.f, va3 = 0.f;
    float vb0 = 0.f, vb1 = 0.f, vb2 = 0.f, vb3 = 0.f;

    while (basea < e1a || baseb < e1b) {
      int cnta = min(32, e1a - basea);
      int cntb = min(32, e1b - baseb);
      int esa = 0, esb = 0;
      if (basea + l < e1a) esa = edge_src[basea + l] * 16;
      if (baseb + l < e1b) esb = edge_src[baseb + l] * 16;

      if (cnta > 0) {
        int s0 = __shfl(esa, ei, 32);
        float4 f0 = make_float4(0.f, 0.f, 0.f, 0.f);
        if (ei < cnta) f0 = *(const float4*)(Yp + s0 + q4);
        if (cnta > 8) {
          int s1 = __shfl(esa, 8 + ei, 32);
          float4 f1 = make_float4(0.f, 0.f, 0.f, 0.f);
          if (8 + ei < cnta) f1 = *(const float4*)(Yp + s1 + q4);
          f0.x += f1.x; f0.y += f1.y; f0.z += f1.z; f0.w += f1.w;
        }
        if (cnta > 16) {
          int s2 = __shfl(esa, 16 + ei, 32);
          int s3 = __shfl(esa, 24 + ei, 32);
          float4 f2 = make_float4(0.f, 0.f, 0.f, 0.f), f3 = f2;
          if (16 + ei < cnta) f2 = *(const float4*)(Yp + s2 + q4);
          if (24 + ei < cnta) f3 = *(const float4*)(Yp + s3 + q4);
          f0.x += f2.x + f3.x; f0.y += f2.y + f3.y;
          f0.z += f2.z + f3.z; f0.w += f2.w + f3.w;
        }
        va0 += f0.x; va1 += f0.y; va2 += f0.z; va3 += f0.w;
      }
      if (cntb > 0) {
        int s0 = __shfl(esb, ei, 32);
        float4 f0 = make_float4(0.f, 0.f, 0.f, 0.f);
        if (ei < cntb) f0 = *(const float4*)(Yp + s0 + q4);
        if (cntb > 8) {
          int s1 = __shfl(esb, 8 + ei, 32);
          float4 f1 = make_float4(0.f, 0.f, 0.f, 0.f);
          if (8 + ei < cntb) f1 = *(const float4*)(Yp + s1 + q4);
          f0.x += f1.x; f0.y += f1.y; f0.z += f1.z; f0.w += f1.w;
        }
        if (cntb > 16) {
          int s2 = __shfl(esb, 16 + ei, 32);
          int s3 = __shfl(esb, 24 + ei, 32);
          float4 f2 = make_float4(0.f, 0.f, 0.f, 0.f), f3 = f2;
          if (16 + ei < cntb) f2 = *(const float4*)(Yp + s2 + q4);
          if (24 + ei < cntb) f3 = *(const float4*)(Yp + s3 + q4);
          f0.x += f2.x + f3.x; f0.y += f2.y + f3.y;
          f0.z += f2.z + f3.z; f0.w += f2.w + f3.w;
        }
        vb0 += f0.x; vb1 += f0.y; vb2 += f0.z; vb3 += f0.w;
      }
      basea += 32; baseb += 32;
    }

    // reduce across the 8 edge slots (lanes 4k+q -> lanes 0..3)
    va0 += __shfl(va0, l + 16, 32); va1 += __shfl(va1, l + 16, 32);
    va2 += __shfl(va2, l + 16, 32); va3 += __shfl(va3, l + 16, 32);
    va0 += __shfl(va0, l + 8, 32);  va1 += __shfl(va1, l + 8, 32);
    va2 += __shfl(va2, l + 8, 32);  va3 += __shfl(va3, l + 8, 32);
    va0 += __shfl(va0, l + 4, 32);  va1 += __shfl(va1, l + 4, 32);
    va2 += __shfl(va2, l + 4, 32);  va3 += __shfl(va3, l + 4, 32);

    vb0 += __shfl(vb0, l + 16, 32); vb1 += __shfl(vb1, l + 16, 32);
    vb2 += __shfl(vb2, l + 16, 32); vb3 += __shfl(vb3, l + 16, 32);
    vb0 += __shfl(vb0, l + 8, 32);  vb1 += __shfl(vb1, l + 8, 32);
    vb2 += __shfl(vb2, l + 8, 32);  vb3 += __shfl(vb3, l + 8, 32);
    vb0 += __shfl(vb0, l + 4, 32);  vb1 += __shfl(vb1, l + 4, 32);
    vb2 += __shfl(vb2, l + 4, 32);  vb3 += __shfl(vb3, l + 4, 32);

    if (l < 4) {
      float ni = norm_in[n], c = cw[n];
      a0 += c * fmaxf(fmaf(ni, va0, b4.x), 0.f);
      a1 += c * fmaxf(fmaf(ni, va1, b4.y), 0.f);
      a2 += c * fmaxf(fmaf(ni, va2, b4.z), 0.f);
      a3 += c * fmaxf(fmaf(ni, va3, b4.w), 0.f);
      if (hb) {
        float nib = norm_in[m], cb = cw[m];
        a0 += cb * fmaxf(fmaf(nib, vb0, b4.x), 0.f);
        a1 += cb * fmaxf(fmaf(nib, vb1, b4.y), 0.f);
        a2 += cb * fmaxf(fmaf(nib, vb2, b4.z), 0.f);
        a3 += cb * fmaxf(fmaf(nib, vb3, b4.w), 0.f);
      }
    }
  }

  if (l < 4) {
    atomicAdd(&red[4 * l + 0], a0);
    atomicAdd(&red[4 * l + 1], a1);
    atomicAdd(&red[4 * l + 2], a2);
    atomicAdd(&red[4 * l + 3], a3);
  }
  __syncthreads();
  if (tid < 16) atomicAdd(&svec[16 * panel + tid], red[tid]);
}

// hg = (svec/N) @ W2 + b2 ; out = hg @ Wr^T + br
__global__ void k_final(const float* __restrict__ svec,
                        const float* __restrict__ W2, const float* __restrict__ b2,
                        const float* __restrict__ Wr, const float* __restrict__ br,
                        float* __restrict__ out) {
  __shared__ float hg[96];
  int j = threadIdx.x;
  if (j < 96) {
    float acc = b2[j];
    const float invN = 1.0f / (float)NN;
    for (int k = 0; k < 96; ++k)
      acc = fmaf(svec[k] * invN, W2[k * 96 + j], acc);
    hg[j] = acc;
  }
  __syncthreads();
  if (j < 8) {
    float acc = br[j];
    for (int k = 0; k < 96; ++k)
      acc = fmaf(hg[k], Wr[j * 96 + k], acc);
    out[j] = acc;
  }
}

extern "C" void kernel_launch(void* const* d_in, const int* in_sizes, int n_in,
                              void* d_out, int out_size, void* d_ws, size_t ws_size,
                              hipStream_t stream) {
  const float* feats = (const float*)d_in[0];
  const int*   src   = (const int*)d_in[1];
  const int*   dst   = (const int*)d_in[2];
  const float* W1    = (const float*)d_in[3];
  const float* b1    = (const float*)d_in[4];
  const float* W2    = (const float*)d_in[5];
  const float* b2    = (const float*)d_in[6];
  const float* Wr    = (const float*)d_in[7];
  const float* br    = (const float*)d_in[8];
  float* out = (float*)d_out;

  int*   wsi      = (int*)d_ws;
  float* wsf      = (float*)d_ws;
  float* svec     = wsf + OFF_SVEC;
  int*   bcur_d   = wsi + OFF_BCURD;
  int*   bcur_s   = wsi + OFF_BCURS;
  float* norm_out = wsf + OFF_NORM_OUT;
  float* norm_in  = wsf + OFF_NORM_IN;
  float* cw       = wsf + OFF_CW;
  int*   row_ptr  = wsi + OFF_ROW_PTR;
  unsigned short* edge_src = (unsigned short*)(wsi + OFF_EDGE_SRC);
  int*   pd       = wsi + OFF_PD;
  int*   ps       = wsi + OFF_PS;
  float* YP       = wsf + OFF_YP;        // aliases pd+ps (both dead by k_xform)

  hipMemsetAsync(d_ws, 0, ZERO_BYTES, stream);   // svec + padded cursors

  k_part<<<(NE + 2047) / 2048, 256, 0, stream>>>(src, dst, bcur_d, bcur_s, pd, ps);
  k_csr<<<NB, 256, 0, stream>>>(pd, bcur_d, row_ptr, norm_in, edge_src);
  k_bin_src<<<NB, 256, 0, stream>>>(ps, bcur_s, norm_in, norm_out, cw);
  k_xform<<<(NN + 63) / 64, 256, 0, stream>>>(feats, norm_out, W1, YP);
  k_agg<<<2048, 256, 0, stream>>>(YP, norm_in, cw, row_ptr, edge_src, b1, svec);
  k_final<<<1, 128, 0, stream>>>(svec, W2, b2, Wr, br, out);
}